// Round 11
// baseline (4821.745 us; speedup 1.0000x reference)
//
#include <hip/hip_runtime.h>
#include <cmath>

#define NB   32
#define TE   128
#define TD   32
#define VOC  32000
#define EMB  256
#define HH   512
#define CTXD 1024
#define DCW  1536   // dcat row: [ctx 1024 | h 512] (ctx slots unused now)

// ws float offsets. ints 0..2047: barrier regions, 16 groups x 128 ints
// (8 lines x 16 ints each): scan groups 0-7 @0, dec groups 0-7 @1024.
#define OHS  2048                        // harr [2][129][NB][HH] (scan only)
#define OEO  (OHS + 2*129*NB*HH)         // enc_out [NB][TE][CTXD]
#define OEP  (OEO + NB*TE*CTXD)          // epre [NB][TE][8]
#define ODC  (OEP + NB*TE*8)             // dcat [TD+1][NB][DCW]
#define WSEND (ODC + (TD+1)*NB*DCW)      // ~40.3MB

__device__ __forceinline__ float sigf(float x) { return 1.0f / (1.0f + expf(-x)); }
__device__ __forceinline__ float hsum4(float4 v) { return (v.x + v.y) + (v.z + v.w); }

__device__ __forceinline__ void stg1(float* p, float v) {
  __hip_atomic_store(p, v, __ATOMIC_RELAXED, __HIP_MEMORY_SCOPE_AGENT);
}

__device__ __forceinline__ void fma4(float4& a, const float4 w, const float4 u) {
  a.x = fmaf(w.x, u.x, a.x); a.y = fmaf(w.y, u.y, a.y);
  a.z = fmaf(w.z, u.z, a.z); a.w = fmaf(w.w, u.w, a.w);
}

// Group-local distributed monotonic barrier (R9 verbatim): 32 participants,
// arrivals over 8 cache lines, wave 0 polls 8 lines with s_sleep throttle
// (R10 showed busy-spin REGRESSES). All-relaxed (agent-acquire = buffer_inv
// sc1 = L2 nuke, R2 regression). __syncthreads drains vmcnt (sc1 stores at
// L3) before arrival; cross-block data read at per-step-fresh addresses.
__device__ __forceinline__ void gbarG(int* bar, int idx, int target) {
  __syncthreads();
  if (threadIdx.x == 0) {
    __hip_atomic_fetch_add(bar + (idx & 7) * 16, 1,
                           __ATOMIC_RELAXED, __HIP_MEMORY_SCOPE_AGENT);
  }
  if (threadIdx.x < 64) {
    const int ln = threadIdx.x;
    int it = 0;
    while (true) {
      int v = (ln < 8)
        ? __hip_atomic_load(bar + ln * 16, __ATOMIC_RELAXED, __HIP_MEMORY_SCOPE_AGENT)
        : 0;
      v += __shfl_xor(v, 1); v += __shfl_xor(v, 2); v += __shfl_xor(v, 4);
      v = __shfl(v, 0);
      if (v >= target) break;
      __builtin_amdgcn_s_sleep(1);
      if (++it > (1 << 20)) break;  // safety bail: garbage beats hang
    }
  }
  __syncthreads();
}

// ---------------- BiLSTM scan: 256 blocks x 512 thr (R9 verbatim) ----------------
__global__ void __launch_bounds__(512)
scan_kernel(const int* __restrict__ enc_in, const int* __restrict__ lens,
            const float* __restrict__ emb_src,
            const float* __restrict__ Wih_f, const float* __restrict__ Whh_f,
            const float* __restrict__ bih_f, const float* __restrict__ bhh_f,
            const float* __restrict__ Wih_b, const float* __restrict__ Whh_b,
            const float* __restrict__ bih_b, const float* __restrict__ bhh_b,
            float* __restrict__ ws)
{
  const int tid = threadIdx.x, bid = blockIdx.x;
  const int g = bid & 7, cg = bid >> 3;
  const int dir = g >> 2, bg = g & 3;
  int* bar = (int*)ws + g * 128;
  float* harr = ws + OHS;
  float* eo   = ws + OEO;

  asm volatile("buffer_inv sc1" ::: "memory");  // purge stale clean lines (graph replays)

  __shared__ int   tokL[TE][8];
  __shared__ float lds_p[8][4][68];

  for (int i = tid; i < TE * 8; i += 512) {
    int bb = i & 7, s = i >> 3;
    int b = bg * 8 + bb;
    int t = s;
    if (dir) { int L = lens[b]; t = (s < L) ? (L - 1 - s) : s; }
    tokL[s][bb] = enc_in[b * TE + t];
  }
  if (tid < 128) {
    int bb = tid >> 4, col = tid & 15;
    stg1(&harr[((size_t)(dir * 129) * NB + bg * 8 + bb) * HH + cg * 16 + col], 0.0f);
  }

  const int lane = tid & 63, w = tid >> 6;
  const int ks = w & 3, rh = w >> 2;
  const int rq = lane >> 4, kl = lane & 15;
  const int j0 = cg * 16;
  const float* Wih = dir ? Wih_b : Wih_f;
  const float* Whh = dir ? Whh_b : Whh_f;

  float4 Wreg[8][3];
  #pragma unroll
  for (int ri = 0; ri < 8; ++ri) {
    int r = rh * 32 + rq * 8 + ri;
    int o = (r >> 4) * HH + j0 + (r & 15);
    #pragma unroll
    for (int p = 0; p < 3; ++p) {
      int kf = (ks * 3 + p) * 16 + kl;
      Wreg[ri][p] = (kf < 64)
        ? *((const float4*)Wih + (size_t)o * 64 + kf)
        : *((const float4*)Whh + (size_t)o * 128 + (kf - 64));
    }
  }

  const int b_u = tid >> 4, col_u = tid & 15;
  const int j_u = j0 + col_u;
  const int bglob = bg * 8 + b_u;
  const int Lu = (tid < 128) ? lens[bglob] : 0;
  float bs0 = 0, bs1 = 0, bs2 = 0, bs3 = 0;
  if (tid < 128) {
    const float* bih = dir ? bih_b : bih_f;
    const float* bhh = dir ? bhh_b : bhh_f;
    bs0 = bih[j_u] + bhh[j_u];
    bs1 = bih[HH + j_u] + bhh[HH + j_u];
    bs2 = bih[2 * HH + j_u] + bhh[2 * HH + j_u];
    bs3 = bih[3 * HH + j_u] + bhh[3 * HH + j_u];
  }
  float cst = 0.0f;

  int tgt = 32;
  gbarG(bar, cg, tgt); tgt += 32;

  for (int s = 0; s < TE; ++s) {
    const float4* h4 = (const float4*)(harr + ((size_t)(dir * 129 + s) * NB) * HH);
    #pragma unroll 2
    for (int bb = 0; bb < 8; ++bb) {
      const int b = bg * 8 + bb;
      const int tok = tokL[s][bb];
      const float4* x4 = (const float4*)emb_src + (size_t)tok * 64;
      float4 u[3];
      #pragma unroll
      for (int p = 0; p < 3; ++p) {
        int c = ks * 3 + p;
        u[p] = (c < 4) ? x4[c * 16 + kl]
                       : h4[(size_t)b * 128 + (c - 4) * 16 + kl];
      }
      float sc[8];
      #pragma unroll
      for (int ri = 0; ri < 8; ++ri) {
        float4 a = {0, 0, 0, 0};
        fma4(a, Wreg[ri][0], u[0]);
        fma4(a, Wreg[ri][1], u[1]);
        fma4(a, Wreg[ri][2], u[2]);
        sc[ri] = hsum4(a);
      }
      #pragma unroll
      for (int ri = 0; ri < 8; ++ri) {
        sc[ri] += __shfl_xor(sc[ri], 1);
        sc[ri] += __shfl_xor(sc[ri], 2);
        sc[ri] += __shfl_xor(sc[ri], 4);
        sc[ri] += __shfl_xor(sc[ri], 8);
      }
      if (kl == 0) {
        int r0 = rh * 32 + rq * 8;
        float4 lo = {sc[0], sc[1], sc[2], sc[3]};
        float4 hi = {sc[4], sc[5], sc[6], sc[7]};
        *(float4*)&lds_p[bb][ks][r0]     = lo;
        *(float4*)&lds_p[bb][ks][r0 + 4] = hi;
      }
    }
    __syncthreads();

    if (tid < 128) {
      float gi = bs0, gf = bs1, gg = bs2, go = bs3;
      #pragma unroll
      for (int k2 = 0; k2 < 4; ++k2) {
        gi += lds_p[b_u][k2][col_u];
        gf += lds_p[b_u][k2][16 + col_u];
        gg += lds_p[b_u][k2][32 + col_u];
        go += lds_p[b_u][k2][48 + col_u];
      }
      float c = sigf(gf) * cst + sigf(gi) * tanhf(gg);
      cst = c;
      float h = sigf(go) * tanhf(c);
      stg1(&harr[((size_t)(dir * 129 + s + 1) * NB + bglob) * HH + j_u], h);
      float hm = (s < Lu) ? h : 0.0f;
      int pos = dir ? ((s < Lu) ? (Lu - 1 - s) : s) : s;
      eo[((size_t)bglob * TE + pos) * CTXD + dir * HH + j_u] = hm;
    }
    gbarG(bar, cg, tgt); tgt += 32;
  }
}

// ---------------- Decoder: 256 blocks x 512 thr, ONE sync/step ----------------
// group g = bid&7: 4 batches; cg = bid>>3: 16 GRU cols (48 gate rows rr=gate*16+col).
// Pre-phase: ep (as before) + VeoL[b][t][rr] = Wc_row . eo[b][t] in LDS (bf16,
// 48KB). In-loop, ctx NEVER crosses blocks: Wc.ctx = sum_t a_t*Veo (linearity).
// Only h_s crosses (dcat, sc1) -> single barrier per step.
__global__ void __launch_bounds__(512)
dec_kernel(const int* __restrict__ dec_in, const int* __restrict__ lens,
           const float* __restrict__ emb_tgt,
           const float* __restrict__ gWih, const float* __restrict__ gWhh,
           const float* __restrict__ gbih, const float* __restrict__ gbhh,
           const float* __restrict__ attn_W, const float* __restrict__ attn_b,
           const float* __restrict__ attn_v,
           float* __restrict__ ws)
{
  const int tid = threadIdx.x, bid = blockIdx.x;
  const int g = bid & 7, cg = bid >> 3;
  const int B4 = g * 4;
  int* bar = (int*)ws + 1024 + g * 128;
  float* eo   = ws + OEO;
  float* ep   = ws + OEP;
  float* dcat = ws + ODC;

  asm volatile("buffer_inv sc1" ::: "memory");

  __shared__ unsigned short VeoL[4][TE][48];   // 48KB bf16
  __shared__ float hl[4][520];
  __shared__ int   tokD[TD][4];
  __shared__ int   lensh[4];
  __shared__ float av8v[8];
  __shared__ float hpv[4][8];
  __shared__ float elds[4][128];
  __shared__ float wlds[4][128];
  __shared__ float mxs[4], invs[4];
  __shared__ float gvc[4][48];
  __shared__ float lds_pd[2][4][4][52];

  for (int i = tid; i < TD * 4; i += 512)
    tokD[i >> 2][i & 3] = dec_in[(B4 + (i & 3)) * TD + (i >> 2)];
  if (tid < 8) av8v[tid] = attn_v[tid];
  if (tid < 4) lensh[tid] = lens[B4 + tid];

  // h0 = 0: each block publishes its own 16-col slice
  if (tid < 64) {
    int bb = tid >> 4, col = tid & 15;
    stg1(&dcat[((size_t)0 * NB + B4 + bb) * DCW + CTXD + cg * 16 + col], 0.0f);
  }

  // ep pre-phase (blocks cg<8 of each group)
  {
    const int idx = cg * 512 + tid;
    if (idx < 4 * TE * 8) {
      int a = idx & 7, t = (idx >> 3) & 127, bb = idx >> 10;
      int b = B4 + bb;
      float acc = attn_b[a];
      const float* er = &eo[((size_t)b * TE + t) * CTXD];
      for (int d = 0; d < CTXD; d += 4) {
        float4 ev = *(const float4*)&er[d];
        acc = fmaf(ev.x, attn_W[(d + 0) * 8 + a], acc);
        acc = fmaf(ev.y, attn_W[(d + 1) * 8 + a], acc);
        acc = fmaf(ev.z, attn_W[(d + 2) * 8 + a], acc);
        acc = fmaf(ev.w, attn_W[(d + 3) * 8 + a], acc);
      }
      stg1(&ep[((size_t)b * TE + t) * 8 + a], acc);
    }
  }

  // Veo precompute: thread (i48 = tid>>3, kc = tid&7), tid<384.
  // VeoL[bb][t][rr] = dot(Wc[row rr], eo[b][t]) over ctx k (1024), k-split 8.
  if (tid < 384) {
    const int i48 = tid >> 3, kc = tid & 7;
    const int row = (i48 >> 4) * HH + cg * 16 + (i48 & 15);
    float4 Wcr[32];
    const float4* wsrc = (const float4*)(gWih + (size_t)row * (EMB + CTXD) + 256 + kc * 128);
    #pragma unroll
    for (int j = 0; j < 32; ++j) Wcr[j] = wsrc[j];
    for (int bb = 0; bb < 4; ++bb) {
      const float4* eob = (const float4*)(eo + ((size_t)(B4 + bb) * TE) * CTXD) + kc * 32;
      for (int t = 0; t < TE; ++t) {
        const float4* er = eob + (size_t)t * 256;
        float4 A = {0,0,0,0}, Bv = {0,0,0,0};
        #pragma unroll
        for (int j = 0; j < 32; j += 2) { fma4(A, Wcr[j], er[j]); fma4(Bv, Wcr[j + 1], er[j + 1]); }
        float sum = hsum4(A) + hsum4(Bv);
        sum += __shfl_xor(sum, 1);
        sum += __shfl_xor(sum, 2);
        sum += __shfl_xor(sum, 4);
        if (kc == 0) {
          unsigned int u = __float_as_uint(sum);
          u = (u + 0x7FFF + ((u >> 16) & 1)) >> 16;  // round-to-nearest bf16
          VeoL[bb][t][i48] = (unsigned short)u;
        }
      }
    }
  }

  // x/h gate weights in regs: waves (ks = w&3, rh = w>>2); lane rq(4) x kl(16).
  // rows rr = rh*24 + rq*6 + ri; u chunks c = ks*3+p (64 wide): c<4 -> x, else h.
  const int lane = tid & 63, w = tid >> 6;
  const int ks = w & 3, rh = w >> 2;
  const int rq = lane >> 4, kl = lane & 15;
  float4 Wreg[6][3];
  #pragma unroll
  for (int ri = 0; ri < 6; ++ri) {
    int rr = rh * 24 + rq * 6 + ri;
    int row = (rr >> 4) * HH + cg * 16 + (rr & 15);
    #pragma unroll
    for (int p = 0; p < 3; ++p) {
      int c = ks * 3 + p;
      Wreg[ri][p] = (c < 4)
        ? *(const float4*)(gWih + (size_t)row * (EMB + CTXD) + c * 64 + kl * 4)
        : *(const float4*)(gWhh + (size_t)row * HH + (c - 4) * 64 + kl * 4);
    }
  }

  // updater (tid<64): (ub = tid>>4 batch, ucol = tid&15)
  const int ub = tid >> 4, ucol = tid & 15;
  const int uj = cg * 16 + ucol;
  float bRc = 0, bZc = 0, bNi = 0, bNh = 0;
  if (tid < 64) {
    bRc = gbih[uj] + gbhh[uj];
    bZc = gbih[HH + uj] + gbhh[HH + uj];
    bNi = gbih[2 * HH + uj];
    bNh = gbhh[2 * HH + uj];
  }

  int tgt = 32;
  gbarG(bar, cg, tgt); tgt += 32;   // ep, h0, VeoL ready

  for (int s = 0; s < TD; ++s) {
    // stage h_s into LDS
    {
      int bb = tid >> 7, c4 = (tid & 127) * 4;
      *(float4*)&hl[bb][c4] =
        *(const float4*)&dcat[((size_t)s * NB + B4 + bb) * DCW + CTXD + c4];
    }
    __syncthreads();
    // hpv: wave w -> batch w>>1, a-half w&1 (from hl)
    {
      const int bb = w >> 1;
      const float4* h4 = (const float4*)&hl[bb][0];
      float4 ha = h4[lane * 2], hb = h4[lane * 2 + 1];
      #pragma unroll
      for (int i = 0; i < 4; ++i) {
        const int a = (w & 1) * 4 + i;
        const float* wa = attn_W + (size_t)(CTXD + lane * 8) * 8 + a;
        float acc = 0.0f;
        acc = fmaf(ha.x, wa[0],  acc); acc = fmaf(ha.y, wa[8],  acc);
        acc = fmaf(ha.z, wa[16], acc); acc = fmaf(ha.w, wa[24], acc);
        acc = fmaf(hb.x, wa[32], acc); acc = fmaf(hb.y, wa[40], acc);
        acc = fmaf(hb.z, wa[48], acc); acc = fmaf(hb.w, wa[56], acc);
        acc += __shfl_xor(acc, 1);  acc += __shfl_xor(acc, 2);
        acc += __shfl_xor(acc, 4);  acc += __shfl_xor(acc, 8);
        acc += __shfl_xor(acc, 16); acc += __shfl_xor(acc, 32);
        if (lane == 0) hpv[bb][a] = acc;
      }
    }
    __syncthreads();
    // scores
    {
      const int bb = tid >> 7, t = tid & 127;
      const int b = B4 + bb;
      float evv = -1e9f;
      if (t < lensh[bb]) {
        const float* e8 = &ep[((size_t)b * TE + t) * 8];
        float4 ea = *(const float4*)e8, eb2 = *(const float4*)(e8 + 4);
        evv  = tanhf(ea.x + hpv[bb][0]) * av8v[0];
        evv += tanhf(ea.y + hpv[bb][1]) * av8v[1];
        evv += tanhf(ea.z + hpv[bb][2]) * av8v[2];
        evv += tanhf(ea.w + hpv[bb][3]) * av8v[3];
        evv += tanhf(eb2.x + hpv[bb][4]) * av8v[4];
        evv += tanhf(eb2.y + hpv[bb][5]) * av8v[5];
        evv += tanhf(eb2.z + hpv[bb][6]) * av8v[6];
        evv += tanhf(eb2.w + hpv[bb][7]) * av8v[7];
      }
      elds[bb][t] = evv;
    }
    __syncthreads();
    if (tid < 256) {
      const int bb = tid >> 6, i = tid & 63;
      float m = fmaxf(elds[bb][i], elds[bb][i + 64]);
      m = fmaxf(m, __shfl_xor(m, 1));  m = fmaxf(m, __shfl_xor(m, 2));
      m = fmaxf(m, __shfl_xor(m, 4));  m = fmaxf(m, __shfl_xor(m, 8));
      m = fmaxf(m, __shfl_xor(m, 16)); m = fmaxf(m, __shfl_xor(m, 32));
      if (i == 0) mxs[bb] = m;
    }
    __syncthreads();
    {
      const int bb = tid >> 7, t = tid & 127;
      wlds[bb][t] = expf(elds[bb][t] - mxs[bb]);
    }
    __syncthreads();
    if (tid < 256) {
      const int bb = tid >> 6, i = tid & 63;
      float sm = wlds[bb][i] + wlds[bb][i + 64];
      sm += __shfl_xor(sm, 1);  sm += __shfl_xor(sm, 2);
      sm += __shfl_xor(sm, 4);  sm += __shfl_xor(sm, 8);
      sm += __shfl_xor(sm, 16); sm += __shfl_xor(sm, 32);
      if (i == 0) invs[bb] = 1.0f / sm;
    }
    // x/h dots -> lds_pd (reg weights; hl LDS for h, emb row for x)
    {
      #pragma unroll
      for (int bb = 0; bb < 4; ++bb) {
        const float4* xr = (const float4*)(emb_tgt + (size_t)tokD[s][bb] * EMB);
        float4 u[3];
        #pragma unroll
        for (int p = 0; p < 3; ++p) {
          int c = ks * 3 + p;
          u[p] = (c < 4) ? xr[c * 16 + kl]
                         : *(const float4*)&hl[bb][(c - 4) * 64 + kl * 4];
        }
        float sI[6], sH[6];
        #pragma unroll
        for (int ri = 0; ri < 6; ++ri) {
          float4 aI = {0,0,0,0}, aH = {0,0,0,0};
          #pragma unroll
          for (int p = 0; p < 3; ++p) {
            int c = ks * 3 + p;
            if (c < 4) fma4(aI, Wreg[ri][p], u[p]);
            else       fma4(aH, Wreg[ri][p], u[p]);
          }
          sI[ri] = hsum4(aI); sH[ri] = hsum4(aH);
        }
        #pragma unroll
        for (int ri = 0; ri < 6; ++ri) {
          sI[ri] += __shfl_xor(sI[ri], 1); sH[ri] += __shfl_xor(sH[ri], 1);
          sI[ri] += __shfl_xor(sI[ri], 2); sH[ri] += __shfl_xor(sH[ri], 2);
          sI[ri] += __shfl_xor(sI[ri], 4); sH[ri] += __shfl_xor(sH[ri], 4);
          sI[ri] += __shfl_xor(sI[ri], 8); sH[ri] += __shfl_xor(sH[ri], 8);
        }
        if (kl == 0) {
          int r0 = rh * 24 + rq * 6;
          #pragma unroll
          for (int ri = 0; ri < 6; ++ri) {
            lds_pd[0][bb][ks][r0 + ri] = sI[ri];
            lds_pd[1][bb][ks][r0 + ri] = sH[ri];
          }
        }
      }
    }
    __syncthreads();
    // ctx-gate part via Veo: gvc[bb][rr] = invs * sum_t wlds[t]*Veo[bb][t][rr]
    {
      const int bb = tid >> 7, idx = tid & 127;
      if (idx < 96) {
        const int rr = idx >> 1, th = idx & 1;
        float acc = 0.0f;
        #pragma unroll 4
        for (int i = 0; i < 64; ++i) {
          int t = th * 64 + i;
          unsigned int u = VeoL[bb][t][rr];
          acc = fmaf(wlds[bb][t], __uint_as_float(u << 16), acc);
        }
        acc += __shfl_xor(acc, 1);
        if (th == 0) gvc[bb][rr] = acc * invs[bb];
      }
    }
    __syncthreads();
    // gate assembly + GRU nonlinearity + publish h_{s+1}
    if (tid < 64) {
      float giR = gvc[ub][ucol], ghR = 0;
      float giZ = gvc[ub][16 + ucol], ghZ = 0;
      float giN = gvc[ub][32 + ucol], ghN = 0;
      #pragma unroll
      for (int k2 = 0; k2 < 4; ++k2) {
        giR += lds_pd[0][ub][k2][ucol];      ghR += lds_pd[1][ub][k2][ucol];
        giZ += lds_pd[0][ub][k2][16 + ucol]; ghZ += lds_pd[1][ub][k2][16 + ucol];
        giN += lds_pd[0][ub][k2][32 + ucol]; ghN += lds_pd[1][ub][k2][32 + ucol];
      }
      float r = sigf(giR + ghR + bRc);
      float z = sigf(giZ + ghZ + bZc);
      float n = tanhf(giN + bNi + r * (ghN + bNh));
      float hnew = (1.0f - z) * n + z * hl[ub][uj];
      stg1(&dcat[((size_t)(s + 1) * NB + B4 + ub) * DCW + CTXD + uj], hnew);
    }
    gbarG(bar, cg, tgt); tgt += 32;   // h_{s+1} visible group-wide
  }
}

// ---------------- Classifier: [1024,512] @ clf_W^T [512,32000], relu --------
// 128x128 tile, 256 thr, 8x8 acc/thread (R9 verbatim).
__global__ void __launch_bounds__(256)
clf_kernel(const float* __restrict__ dcat, const float* __restrict__ W,
           const float* __restrict__ bias, float* __restrict__ out)
{
  asm volatile("buffer_inv sc1" ::: "memory");
  __shared__ __align__(16) float As[16][132];
  __shared__ __align__(16) float Bs[16][132];
  const int tid = threadIdx.x;
  const int tx = tid & 15, ty = tid >> 4;
  const int n0 = blockIdx.x * 128, m0 = blockIdx.y * 128;
  float acc[8][8] = {};
  const int lr = tid >> 1;
  const int lk = (tid & 1) * 8;
  const int r  = m0 + lr;
  const float* arow = dcat + ((size_t)((r & 31) + 1) * NB + (r >> 5)) * DCW + CTXD;
  const float* brow = W + (size_t)(n0 + lr) * HH;

  for (int kc = 0; kc < HH; kc += 16) {
    float4 av0 = *(const float4*)&arow[kc + lk];
    float4 av1 = *(const float4*)&arow[kc + lk + 4];
    float4 bv0 = *(const float4*)&brow[kc + lk];
    float4 bv1 = *(const float4*)&brow[kc + lk + 4];
    __syncthreads();
    As[lk + 0][lr] = av0.x; As[lk + 1][lr] = av0.y;
    As[lk + 2][lr] = av0.z; As[lk + 3][lr] = av0.w;
    As[lk + 4][lr] = av1.x; As[lk + 5][lr] = av1.y;
    As[lk + 6][lr] = av1.z; As[lk + 7][lr] = av1.w;
    Bs[lk + 0][lr] = bv0.x; Bs[lk + 1][lr] = bv0.y;
    Bs[lk + 2][lr] = bv0.z; Bs[lk + 3][lr] = bv0.w;
    Bs[lk + 4][lr] = bv1.x; Bs[lk + 5][lr] = bv1.y;
    Bs[lk + 6][lr] = bv1.z; Bs[lk + 7][lr] = bv1.w;
    __syncthreads();
    #pragma unroll
    for (int kk = 0; kk < 16; ++kk) {
      float a8[8], b8[8];
      *(float4*)&a8[0] = *(const float4*)&As[kk][ty * 8];
      *(float4*)&a8[4] = *(const float4*)&As[kk][ty * 8 + 4];
      *(float4*)&b8[0] = *(const float4*)&Bs[kk][tx * 8];
      *(float4*)&b8[4] = *(const float4*)&Bs[kk][tx * 8 + 4];
      #pragma unroll
      for (int i = 0; i < 8; ++i)
        #pragma unroll
        for (int j = 0; j < 8; ++j)
          acc[i][j] = fmaf(a8[i], b8[j], acc[i][j]);
    }
  }
  const int col = n0 + tx * 8;
  float bb[8];
  *(float4*)&bb[0] = *(const float4*)&bias[col];
  *(float4*)&bb[4] = *(const float4*)&bias[col + 4];
  #pragma unroll
  for (int i = 0; i < 8; ++i) {
    int row = m0 + ty * 8 + i;
    float4 o0, o1;
    o0.x = fmaxf(acc[i][0] + bb[0], 0.0f); o0.y = fmaxf(acc[i][1] + bb[1], 0.0f);
    o0.z = fmaxf(acc[i][2] + bb[2], 0.0f); o0.w = fmaxf(acc[i][3] + bb[3], 0.0f);
    o1.x = fmaxf(acc[i][4] + bb[4], 0.0f); o1.y = fmaxf(acc[i][5] + bb[5], 0.0f);
    o1.z = fmaxf(acc[i][6] + bb[6], 0.0f); o1.w = fmaxf(acc[i][7] + bb[7], 0.0f);
    *(float4*)&out[(size_t)row * VOC + col]     = o0;
    *(float4*)&out[(size_t)row * VOC + col + 4] = o1;
  }
}

extern "C" void kernel_launch(void* const* d_in, const int* in_sizes, int n_in,
                              void* d_out, int out_size, void* d_ws, size_t ws_size,
                              hipStream_t stream)
{
  if (ws_size < (size_t)WSEND * 4) return;  // visible-failure guard

  const int* enc_in  = (const int*)d_in[0];
  const int* enc_len = (const int*)d_in[1];
  const int* dec_in  = (const int*)d_in[2];
  const float* emb_src = (const float*)d_in[4];
  const float* emb_tgt = (const float*)d_in[5];
  const float* Wih_f = (const float*)d_in[6];
  const float* Whh_f = (const float*)d_in[7];
  const float* bih_f = (const float*)d_in[8];
  const float* bhh_f = (const float*)d_in[9];
  const float* Wih_b = (const float*)d_in[10];
  const float* Whh_b = (const float*)d_in[11];
  const float* bih_b = (const float*)d_in[12];
  const float* bhh_b = (const float*)d_in[13];
  const float* gWih  = (const float*)d_in[14];
  const float* gWhh  = (const float*)d_in[15];
  const float* gbih  = (const float*)d_in[16];
  const float* gbhh  = (const float*)d_in[17];
  const float* attn_W = (const float*)d_in[18];
  const float* attn_b = (const float*)d_in[19];
  const float* attn_v = (const float*)d_in[20];
  const float* clf_W = (const float*)d_in[21];
  const float* clf_b = (const float*)d_in[22];
  float* ws  = (float*)d_ws;
  float* out = (float*)d_out;

  hipMemsetAsync(d_ws, 0, 8192, stream);  // barrier lines (16 groups)
  scan_kernel<<<256, 512, 0, stream>>>(enc_in, enc_len, emb_src,
      Wih_f, Whh_f, bih_f, bhh_f, Wih_b, Whh_b, bih_b, bhh_b, ws);
  dec_kernel<<<256, 512, 0, stream>>>(dec_in, enc_len, emb_tgt,
      gWih, gWhh, gbih, gbhh, attn_W, attn_b, attn_v, ws);
  dim3 cg(VOC / 128, (NB * TD) / 128);
  clf_kernel<<<cg, 256, 0, stream>>>(ws + ODC, clf_W, clf_b, out);
}

// Round 12
// 2333.850 us; speedup vs baseline: 2.0660x; 2.0660x over previous
//
#include <hip/hip_runtime.h>
#include <cmath>

#define NB   32
#define TE   128
#define TD   32
#define VOC  32000
#define EMB  256
#define HH   512
#define CTXD 1024
#define NR   1536   // GRU gate rows (3*HH)

// ws float offsets. ints 0..2047: barrier regions, 16 groups x 128 ints
// (8 lines x 16 ints each): scan groups 0-7 @0, dec groups 0-7 @1024.
#define OHS  2048                        // harr [2][129][NB][HH] (scan)
#define OEO  (OHS + 2*129*NB*HH)         // enc_out [NB][TE][CTXD]
#define OEP  (OEO + NB*TE*CTXD)          // epre [NB][TE][8]
#define OHD  (OEP + NB*TE*8)             // hdec [TD+1][NB][HH]
#define OVEO (OHD + (TD+1)*NB*HH)        // veo bf16 [NB][NR][TE] (ushort)
#define WSEND (OVEO + NB*NR*TE/2)        // 12,142,592 floats = 48.57MB

__device__ __forceinline__ float sigf(float x) { return 1.0f / (1.0f + expf(-x)); }
__device__ __forceinline__ float hsum4(float4 v) { return (v.x + v.y) + (v.z + v.w); }

__device__ __forceinline__ void stg1(float* p, float v) {
  __hip_atomic_store(p, v, __ATOMIC_RELAXED, __HIP_MEMORY_SCOPE_AGENT);
}

__device__ __forceinline__ void fma4(float4& a, const float4 w, const float4 u) {
  a.x = fmaf(w.x, u.x, a.x); a.y = fmaf(w.y, u.y, a.y);
  a.z = fmaf(w.z, u.z, a.z); a.w = fmaf(w.w, u.w, a.w);
}

__device__ __forceinline__ unsigned short to_bf16(float f) {
  unsigned int u = __float_as_uint(f);
  u = (u + 0x7FFF + ((u >> 16) & 1)) >> 16;  // round-to-nearest-even
  return (unsigned short)u;
}

// Group-local distributed monotonic barrier (R9 verbatim): 32 participants,
// arrivals over 8 cache lines, wave 0 polls with s_sleep (R10: busy-spin
// REGRESSES). All-relaxed (agent-acquire = buffer_inv sc1 = L2 nuke, R2).
// __syncthreads drains vmcnt (sc1 stores at L3) before arrival; cross-block
// data read at per-step-fresh addresses only.
__device__ __forceinline__ void gbarG(int* bar, int idx, int target) {
  __syncthreads();
  if (threadIdx.x == 0) {
    __hip_atomic_fetch_add(bar + (idx & 7) * 16, 1,
                           __ATOMIC_RELAXED, __HIP_MEMORY_SCOPE_AGENT);
  }
  if (threadIdx.x < 64) {
    const int ln = threadIdx.x;
    int it = 0;
    while (true) {
      int v = (ln < 8)
        ? __hip_atomic_load(bar + ln * 16, __ATOMIC_RELAXED, __HIP_MEMORY_SCOPE_AGENT)
        : 0;
      v += __shfl_xor(v, 1); v += __shfl_xor(v, 2); v += __shfl_xor(v, 4);
      v = __shfl(v, 0);
      if (v >= target) break;
      __builtin_amdgcn_s_sleep(1);
      if (++it > (1 << 20)) break;  // safety bail: garbage beats hang
    }
  }
  __syncthreads();
}

// ---------------- BiLSTM scan: 256 blocks x 512 thr (R9 verbatim) ----------------
__global__ void __launch_bounds__(512)
scan_kernel(const int* __restrict__ enc_in, const int* __restrict__ lens,
            const float* __restrict__ emb_src,
            const float* __restrict__ Wih_f, const float* __restrict__ Whh_f,
            const float* __restrict__ bih_f, const float* __restrict__ bhh_f,
            const float* __restrict__ Wih_b, const float* __restrict__ Whh_b,
            const float* __restrict__ bih_b, const float* __restrict__ bhh_b,
            float* __restrict__ ws)
{
  const int tid = threadIdx.x, bid = blockIdx.x;
  const int g = bid & 7, cg = bid >> 3;
  const int dir = g >> 2, bg = g & 3;
  int* bar = (int*)ws + g * 128;
  float* harr = ws + OHS;
  float* eo   = ws + OEO;

  asm volatile("buffer_inv sc1" ::: "memory");  // purge stale clean lines (graph replays)

  __shared__ int   tokL[TE][8];
  __shared__ float lds_p[8][4][68];

  for (int i = tid; i < TE * 8; i += 512) {
    int bb = i & 7, s = i >> 3;
    int b = bg * 8 + bb;
    int t = s;
    if (dir) { int L = lens[b]; t = (s < L) ? (L - 1 - s) : s; }
    tokL[s][bb] = enc_in[b * TE + t];
  }
  if (tid < 128) {
    int bb = tid >> 4, col = tid & 15;
    stg1(&harr[((size_t)(dir * 129) * NB + bg * 8 + bb) * HH + cg * 16 + col], 0.0f);
  }

  const int lane = tid & 63, w = tid >> 6;
  const int ks = w & 3, rh = w >> 2;
  const int rq = lane >> 4, kl = lane & 15;
  const int j0 = cg * 16;
  const float* Wih = dir ? Wih_b : Wih_f;
  const float* Whh = dir ? Whh_b : Whh_f;

  float4 Wreg[8][3];
  #pragma unroll
  for (int ri = 0; ri < 8; ++ri) {
    int r = rh * 32 + rq * 8 + ri;
    int o = (r >> 4) * HH + j0 + (r & 15);
    #pragma unroll
    for (int p = 0; p < 3; ++p) {
      int kf = (ks * 3 + p) * 16 + kl;
      Wreg[ri][p] = (kf < 64)
        ? *((const float4*)Wih + (size_t)o * 64 + kf)
        : *((const float4*)Whh + (size_t)o * 128 + (kf - 64));
    }
  }

  const int b_u = tid >> 4, col_u = tid & 15;
  const int j_u = j0 + col_u;
  const int bglob = bg * 8 + b_u;
  const int Lu = (tid < 128) ? lens[bglob] : 0;
  float bs0 = 0, bs1 = 0, bs2 = 0, bs3 = 0;
  if (tid < 128) {
    const float* bih = dir ? bih_b : bih_f;
    const float* bhh = dir ? bhh_b : bhh_f;
    bs0 = bih[j_u] + bhh[j_u];
    bs1 = bih[HH + j_u] + bhh[HH + j_u];
    bs2 = bih[2 * HH + j_u] + bhh[2 * HH + j_u];
    bs3 = bih[3 * HH + j_u] + bhh[3 * HH + j_u];
  }
  float cst = 0.0f;

  int tgt = 32;
  gbarG(bar, cg, tgt); tgt += 32;

  for (int s = 0; s < TE; ++s) {
    const float4* h4 = (const float4*)(harr + ((size_t)(dir * 129 + s) * NB) * HH);
    #pragma unroll 2
    for (int bb = 0; bb < 8; ++bb) {
      const int b = bg * 8 + bb;
      const int tok = tokL[s][bb];
      const float4* x4 = (const float4*)emb_src + (size_t)tok * 64;
      float4 u[3];
      #pragma unroll
      for (int p = 0; p < 3; ++p) {
        int c = ks * 3 + p;
        u[p] = (c < 4) ? x4[c * 16 + kl]
                       : h4[(size_t)b * 128 + (c - 4) * 16 + kl];
      }
      float sc[8];
      #pragma unroll
      for (int ri = 0; ri < 8; ++ri) {
        float4 a = {0, 0, 0, 0};
        fma4(a, Wreg[ri][0], u[0]);
        fma4(a, Wreg[ri][1], u[1]);
        fma4(a, Wreg[ri][2], u[2]);
        sc[ri] = hsum4(a);
      }
      #pragma unroll
      for (int ri = 0; ri < 8; ++ri) {
        sc[ri] += __shfl_xor(sc[ri], 1);
        sc[ri] += __shfl_xor(sc[ri], 2);
        sc[ri] += __shfl_xor(sc[ri], 4);
        sc[ri] += __shfl_xor(sc[ri], 8);
      }
      if (kl == 0) {
        int r0 = rh * 32 + rq * 8;
        float4 lo = {sc[0], sc[1], sc[2], sc[3]};
        float4 hi = {sc[4], sc[5], sc[6], sc[7]};
        *(float4*)&lds_p[bb][ks][r0]     = lo;
        *(float4*)&lds_p[bb][ks][r0 + 4] = hi;
      }
    }
    __syncthreads();

    if (tid < 128) {
      float gi = bs0, gf = bs1, gg = bs2, go = bs3;
      #pragma unroll
      for (int k2 = 0; k2 < 4; ++k2) {
        gi += lds_p[b_u][k2][col_u];
        gf += lds_p[b_u][k2][16 + col_u];
        gg += lds_p[b_u][k2][32 + col_u];
        go += lds_p[b_u][k2][48 + col_u];
      }
      float c = sigf(gf) * cst + sigf(gi) * tanhf(gg);
      cst = c;
      float h = sigf(go) * tanhf(c);
      stg1(&harr[((size_t)(dir * 129 + s + 1) * NB + bglob) * HH + j_u], h);
      float hm = (s < Lu) ? h : 0.0f;
      int pos = dir ? ((s < Lu) ? (Lu - 1 - s) : s) : s;
      eo[((size_t)bglob * TE + pos) * CTXD + dir * HH + j_u] = hm;
    }
    gbarG(bar, cg, tgt); tgt += 32;
  }
}

// ------------- Veo GEMM: veo[b][n][t] = gWih[n][256:1280] . eo[b][t] (bf16) ----
// M = 4096 (b*128+t), N = 1536, K = 1024. 128x128 tile, 256 thr, 8x8 acc.
// Output t-contiguous -> coalesced writes; dec reads 128B-contig slices.
__global__ void __launch_bounds__(256)
veo_kernel(const float* __restrict__ eo, const float* __restrict__ gWih,
           unsigned short* __restrict__ veo)
{
  asm volatile("buffer_inv sc1" ::: "memory");
  __shared__ __align__(16) float As[16][132];
  __shared__ __align__(16) float Bs[16][132];
  const int tid = threadIdx.x;
  const int tx = tid & 15, ty = tid >> 4;
  const int n0 = blockIdx.x * 128, m0 = blockIdx.y * 128;
  float acc[8][8] = {};
  const int lr = tid >> 1;
  const int lk = (tid & 1) * 8;
  const float* arow = eo + (size_t)(m0 + lr) * CTXD;
  const float* brow = gWih + (size_t)(n0 + lr) * (EMB + CTXD) + EMB;

  for (int kc = 0; kc < CTXD; kc += 16) {
    float4 av0 = *(const float4*)&arow[kc + lk];
    float4 av1 = *(const float4*)&arow[kc + lk + 4];
    float4 bv0 = *(const float4*)&brow[kc + lk];
    float4 bv1 = *(const float4*)&brow[kc + lk + 4];
    __syncthreads();
    As[lk + 0][lr] = av0.x; As[lk + 1][lr] = av0.y;
    As[lk + 2][lr] = av0.z; As[lk + 3][lr] = av0.w;
    As[lk + 4][lr] = av1.x; As[lk + 5][lr] = av1.y;
    As[lk + 6][lr] = av1.z; As[lk + 7][lr] = av1.w;
    Bs[lk + 0][lr] = bv0.x; Bs[lk + 1][lr] = bv0.y;
    Bs[lk + 2][lr] = bv0.z; Bs[lk + 3][lr] = bv0.w;
    Bs[lk + 4][lr] = bv1.x; Bs[lk + 5][lr] = bv1.y;
    Bs[lk + 6][lr] = bv1.z; Bs[lk + 7][lr] = bv1.w;
    __syncthreads();
    #pragma unroll
    for (int kk = 0; kk < 16; ++kk) {
      float a8[8], b8[8];
      *(float4*)&a8[0] = *(const float4*)&As[kk][ty * 8];
      *(float4*)&a8[4] = *(const float4*)&As[kk][ty * 8 + 4];
      *(float4*)&b8[0] = *(const float4*)&Bs[kk][tx * 8];
      *(float4*)&b8[4] = *(const float4*)&Bs[kk][tx * 8 + 4];
      #pragma unroll
      for (int i = 0; i < 8; ++i)
        #pragma unroll
        for (int j = 0; j < 8; ++j)
          acc[i][j] = fmaf(a8[i], b8[j], acc[i][j]);
    }
  }
  const int b = m0 >> 7;          // one batch per m-tile (TE == tile M)
  #pragma unroll
  for (int j = 0; j < 8; ++j) {
    int n = n0 + tx * 8 + j;
    unsigned short o8[8];
    #pragma unroll
    for (int i = 0; i < 8; ++i) o8[i] = to_bf16(acc[i][j]);
    *(uint4*)&veo[((size_t)b * NR + n) * TE + ty * 8] = *(uint4*)o8;
  }
}

// ---------------- Decoder: 256 blocks x 512 thr, ONE sync/step ----------------
// group g = bid&7: 4 batches; cg = bid>>3: 16 GRU cols (48 gate rows).
// ctx never crosses blocks: Wc.ctx = sum_t a_t * veo[b][row][t] (linearity).
// Only h_s crosses (hdec, sc1) -> single barrier per step.
__global__ void __launch_bounds__(512)
dec_kernel(const int* __restrict__ dec_in, const int* __restrict__ lens,
           const float* __restrict__ emb_tgt,
           const float* __restrict__ gWih, const float* __restrict__ gWhh,
           const float* __restrict__ gbih, const float* __restrict__ gbhh,
           const float* __restrict__ attn_W, const float* __restrict__ attn_b,
           const float* __restrict__ attn_v,
           float* __restrict__ ws)
{
  const int tid = threadIdx.x, bid = blockIdx.x;
  const int g = bid & 7, cg = bid >> 3;
  const int B4 = g * 4;
  int* bar = (int*)ws + 1024 + g * 128;
  float* eo = ws + OEO;
  float* ep = ws + OEP;
  float* hd = ws + OHD;
  const unsigned short* veoH = (const unsigned short*)(ws + OVEO);

  asm volatile("buffer_inv sc1" ::: "memory");

  __shared__ float hl[4][520];
  __shared__ int   tokD[TD][4];
  __shared__ int   lensh[4];
  __shared__ float av8v[8];
  __shared__ float hpv[4][8];
  __shared__ float elds[4][128];
  __shared__ float wlds[4][128];
  __shared__ float mxs[4], invs[4];
  __shared__ float gvc[4][48];
  __shared__ float lds_pd[2][4][4][52];

  for (int i = tid; i < TD * 4; i += 512)
    tokD[i >> 2][i & 3] = dec_in[(B4 + (i & 3)) * TD + (i >> 2)];
  if (tid < 8) av8v[tid] = attn_v[tid];
  if (tid < 4) lensh[tid] = lens[B4 + tid];

  // h0 = 0: each block publishes its own 16-col slice for its 4 batches
  if (tid < 64) {
    int bb = tid >> 4, col = tid & 15;
    stg1(&hd[(size_t)(B4 + bb) * HH + cg * 16 + col], 0.0f);
  }

  // ep pre-phase (blocks cg<8 of each group)
  {
    const int idx = cg * 512 + tid;
    if (idx < 4 * TE * 8) {
      int a = idx & 7, t = (idx >> 3) & 127, bb = idx >> 10;
      int b = B4 + bb;
      float acc = attn_b[a];
      const float* er = &eo[((size_t)b * TE + t) * CTXD];
      for (int d = 0; d < CTXD; d += 4) {
        float4 ev = *(const float4*)&er[d];
        acc = fmaf(ev.x, attn_W[(d + 0) * 8 + a], acc);
        acc = fmaf(ev.y, attn_W[(d + 1) * 8 + a], acc);
        acc = fmaf(ev.z, attn_W[(d + 2) * 8 + a], acc);
        acc = fmaf(ev.w, attn_W[(d + 3) * 8 + a], acc);
      }
      stg1(&ep[((size_t)b * TE + t) * 8 + a], acc);
    }
  }

  // x/h gate weights in regs: waves (ks = w&3, rh = w>>2); lanes (rq, kl).
  const int lane = tid & 63, w = tid >> 6;
  const int ks = w & 3, rh = w >> 2;
  const int rq = lane >> 4, kl = lane & 15;
  float4 Wreg[6][3];
  #pragma unroll
  for (int ri = 0; ri < 6; ++ri) {
    int rr = rh * 24 + rq * 6 + ri;
    int row = (rr >> 4) * HH + cg * 16 + (rr & 15);
    #pragma unroll
    for (int p = 0; p < 3; ++p) {
      int c = ks * 3 + p;
      Wreg[ri][p] = (c < 4)
        ? *(const float4*)(gWih + (size_t)row * (EMB + CTXD) + c * 64 + kl * 4)
        : *(const float4*)(gWhh + (size_t)row * HH + (c - 4) * 64 + kl * 4);
    }
  }

  // updater (tid<64): (ub batch, ucol col)
  const int ub = tid >> 4, ucol = tid & 15;
  const int uj = cg * 16 + ucol;
  float bRc = 0, bZc = 0, bNi = 0, bNh = 0;
  if (tid < 64) {
    bRc = gbih[uj] + gbhh[uj];
    bZc = gbih[HH + uj] + gbhh[HH + uj];
    bNi = gbih[2 * HH + uj];
    bNh = gbhh[2 * HH + uj];
  }

  int tgt = 32;
  gbarG(bar, cg, tgt); tgt += 32;   // ep, h0 visible group-wide

  for (int s = 0; s < TD; ++s) {
    // stage h_s into LDS
    {
      int bb = tid >> 7, c4 = (tid & 127) * 4;
      *(float4*)&hl[bb][c4] =
        *(const float4*)&hd[((size_t)s * NB + B4 + bb) * HH + c4];
    }
    __syncthreads();
    // hpv: wave w -> batch w>>1, a-half w&1
    {
      const int bb = w >> 1;
      const float4* h4 = (const float4*)&hl[bb][0];
      float4 ha = h4[lane * 2], hb = h4[lane * 2 + 1];
      #pragma unroll
      for (int i = 0; i < 4; ++i) {
        const int a = (w & 1) * 4 + i;
        const float* wa = attn_W + (size_t)(CTXD + lane * 8) * 8 + a;
        float acc = 0.0f;
        acc = fmaf(ha.x, wa[0],  acc); acc = fmaf(ha.y, wa[8],  acc);
        acc = fmaf(ha.z, wa[16], acc); acc = fmaf(ha.w, wa[24], acc);
        acc = fmaf(hb.x, wa[32], acc); acc = fmaf(hb.y, wa[40], acc);
        acc = fmaf(hb.z, wa[48], acc); acc = fmaf(hb.w, wa[56], acc);
        acc += __shfl_xor(acc, 1);  acc += __shfl_xor(acc, 2);
        acc += __shfl_xor(acc, 4);  acc += __shfl_xor(acc, 8);
        acc += __shfl_xor(acc, 16); acc += __shfl_xor(acc, 32);
        if (lane == 0) hpv[bb][a] = acc;
      }
    }
    __syncthreads();
    // scores
    {
      const int bb = tid >> 7, t = tid & 127;
      const int b = B4 + bb;
      float evv = -1e9f;
      if (t < lensh[bb]) {
        const float* e8 = &ep[((size_t)b * TE + t) * 8];
        float4 ea = *(const float4*)e8, eb2 = *(const float4*)(e8 + 4);
        evv  = tanhf(ea.x + hpv[bb][0]) * av8v[0];
        evv += tanhf(ea.y + hpv[bb][1]) * av8v[1];
        evv += tanhf(ea.z + hpv[bb][2]) * av8v[2];
        evv += tanhf(ea.w + hpv[bb][3]) * av8v[3];
        evv += tanhf(eb2.x + hpv[bb][4]) * av8v[4];
        evv += tanhf(eb2.y + hpv[bb][5]) * av8v[5];
        evv += tanhf(eb2.z + hpv[bb][6]) * av8v[6];
        evv += tanhf(eb2.w + hpv[bb][7]) * av8v[7];
      }
      elds[bb][t] = evv;
    }
    __syncthreads();
    if (tid < 256) {
      const int bb = tid >> 6, i = tid & 63;
      float m = fmaxf(elds[bb][i], elds[bb][i + 64]);
      m = fmaxf(m, __shfl_xor(m, 1));  m = fmaxf(m, __shfl_xor(m, 2));
      m = fmaxf(m, __shfl_xor(m, 4));  m = fmaxf(m, __shfl_xor(m, 8));
      m = fmaxf(m, __shfl_xor(m, 16)); m = fmaxf(m, __shfl_xor(m, 32));
      if (i == 0) mxs[bb] = m;
    }
    __syncthreads();
    {
      const int bb = tid >> 7, t = tid & 127;
      wlds[bb][t] = expf(elds[bb][t] - mxs[bb]);
    }
    __syncthreads();
    if (tid < 256) {
      const int bb = tid >> 6, i = tid & 63;
      float sm = wlds[bb][i] + wlds[bb][i + 64];
      sm += __shfl_xor(sm, 1);  sm += __shfl_xor(sm, 2);
      sm += __shfl_xor(sm, 4);  sm += __shfl_xor(sm, 8);
      sm += __shfl_xor(sm, 16); sm += __shfl_xor(sm, 32);
      if (i == 0) invs[bb] = 1.0f / sm;
    }
    // x/h dots (indep of wlds; fills the gap before the sync)
    {
      #pragma unroll
      for (int bb = 0; bb < 4; ++bb) {
        const float4* xr = (const float4*)(emb_tgt + (size_t)tokD[s][bb] * EMB);
        float4 u[3];
        #pragma unroll
        for (int p = 0; p < 3; ++p) {
          int c = ks * 3 + p;
          u[p] = (c < 4) ? xr[c * 16 + kl]
                         : *(const float4*)&hl[bb][(c - 4) * 64 + kl * 4];
        }
        float sI[6], sH[6];
        #pragma unroll
        for (int ri = 0; ri < 6; ++ri) {
          float4 aI = {0,0,0,0}, aH = {0,0,0,0};
          #pragma unroll
          for (int p = 0; p < 3; ++p) {
            int c = ks * 3 + p;
            if (c < 4) fma4(aI, Wreg[ri][p], u[p]);
            else       fma4(aH, Wreg[ri][p], u[p]);
          }
          sI[ri] = hsum4(aI); sH[ri] = hsum4(aH);
        }
        #pragma unroll
        for (int ri = 0; ri < 6; ++ri) {
          sI[ri] += __shfl_xor(sI[ri], 1); sH[ri] += __shfl_xor(sH[ri], 1);
          sI[ri] += __shfl_xor(sI[ri], 2); sH[ri] += __shfl_xor(sH[ri], 2);
          sI[ri] += __shfl_xor(sI[ri], 4); sH[ri] += __shfl_xor(sH[ri], 4);
          sI[ri] += __shfl_xor(sI[ri], 8); sH[ri] += __shfl_xor(sH[ri], 8);
        }
        if (kl == 0) {
          int r0 = rh * 24 + rq * 6;
          #pragma unroll
          for (int ri = 0; ri < 6; ++ri) {
            lds_pd[0][bb][ks][r0 + ri] = sI[ri];
            lds_pd[1][bb][ks][r0 + ri] = sH[ri];
          }
        }
      }
    }
    __syncthreads();   // wlds/invs + lds_pd ready
    // ctx-gate via veo (global, bf16, t-contiguous): gvc[bb][rr]
    if (tid < 384) {
      const int bb = tid / 96, idx = tid % 96;
      const int rr = idx >> 1, th = idx & 1;
      const int n = (rr >> 4) * HH + cg * 16 + (rr & 15);
      const unsigned short* vp = veoH + ((size_t)(B4 + bb) * NR + n) * TE + th * 64;
      const float* wl = &wlds[bb][th * 64];
      float acc = 0.0f;
      #pragma unroll
      for (int q = 0; q < 8; ++q) {
        uint4 pk = *(const uint4*)&vp[q * 8];
        unsigned int uu[4] = {pk.x, pk.y, pk.z, pk.w};
        #pragma unroll
        for (int h2 = 0; h2 < 4; ++h2) {
          acc = fmaf(wl[q * 8 + h2 * 2 + 0],
                     __uint_as_float((uu[h2] & 0xFFFFu) << 16), acc);
          acc = fmaf(wl[q * 8 + h2 * 2 + 1],
                     __uint_as_float((uu[h2] >> 16) << 16), acc);
        }
      }
      acc += __shfl_xor(acc, 1);
      if (th == 0) gvc[bb][rr] = acc * invs[bb];
    }
    __syncthreads();
    // gate assembly + GRU nonlinearity + publish h_{s+1}
    if (tid < 64) {
      float giR = gvc[ub][ucol], ghR = 0;
      float giZ = gvc[ub][16 + ucol], ghZ = 0;
      float giN = gvc[ub][32 + ucol], ghN = 0;
      #pragma unroll
      for (int k2 = 0; k2 < 4; ++k2) {
        giR += lds_pd[0][ub][k2][ucol];      ghR += lds_pd[1][ub][k2][ucol];
        giZ += lds_pd[0][ub][k2][16 + ucol]; ghZ += lds_pd[1][ub][k2][16 + ucol];
        giN += lds_pd[0][ub][k2][32 + ucol]; ghN += lds_pd[1][ub][k2][32 + ucol];
      }
      float r = sigf(giR + ghR + bRc);
      float z = sigf(giZ + ghZ + bZc);
      float n = tanhf(giN + bNi + r * (ghN + bNh));
      float hnew = (1.0f - z) * n + z * hl[ub][uj];
      stg1(&hd[((size_t)(s + 1) * NB + B4 + ub) * HH + uj], hnew);
    }
    gbarG(bar, cg, tgt); tgt += 32;   // h_{s+1} visible group-wide
  }
}

// ---------------- Classifier: [1024,512] @ clf_W^T [512,32000], relu --------
// 128x128 tile, 256 thr, 8x8 acc/thread (R9 verbatim, hdec stride HH).
__global__ void __launch_bounds__(256)
clf_kernel(const float* __restrict__ hd, const float* __restrict__ W,
           const float* __restrict__ bias, float* __restrict__ out)
{
  asm volatile("buffer_inv sc1" ::: "memory");
  __shared__ __align__(16) float As[16][132];
  __shared__ __align__(16) float Bs[16][132];
  const int tid = threadIdx.x;
  const int tx = tid & 15, ty = tid >> 4;
  const int n0 = blockIdx.x * 128, m0 = blockIdx.y * 128;
  float acc[8][8] = {};
  const int lr = tid >> 1;
  const int lk = (tid & 1) * 8;
  const int r  = m0 + lr;
  const float* arow = hd + ((size_t)((r & 31) + 1) * NB + (r >> 5)) * HH;
  const float* brow = W + (size_t)(n0 + lr) * HH;

  for (int kc = 0; kc < HH; kc += 16) {
    float4 av0 = *(const float4*)&arow[kc + lk];
    float4 av1 = *(const float4*)&arow[kc + lk + 4];
    float4 bv0 = *(const float4*)&brow[kc + lk];
    float4 bv1 = *(const float4*)&brow[kc + lk + 4];
    __syncthreads();
    As[lk + 0][lr] = av0.x; As[lk + 1][lr] = av0.y;
    As[lk + 2][lr] = av0.z; As[lk + 3][lr] = av0.w;
    As[lk + 4][lr] = av1.x; As[lk + 5][lr] = av1.y;
    As[lk + 6][lr] = av1.z; As[lk + 7][lr] = av1.w;
    Bs[lk + 0][lr] = bv0.x; Bs[lk + 1][lr] = bv0.y;
    Bs[lk + 2][lr] = bv0.z; Bs[lk + 3][lr] = bv0.w;
    Bs[lk + 4][lr] = bv1.x; Bs[lk + 5][lr] = bv1.y;
    Bs[lk + 6][lr] = bv1.z; Bs[lk + 7][lr] = bv1.w;
    __syncthreads();
    #pragma unroll
    for (int kk = 0; kk < 16; ++kk) {
      float a8[8], b8[8];
      *(float4*)&a8[0] = *(const float4*)&As[kk][ty * 8];
      *(float4*)&a8[4] = *(const float4*)&As[kk][ty * 8 + 4];
      *(float4*)&b8[0] = *(const float4*)&Bs[kk][tx * 8];
      *(float4*)&b8[4] = *(const float4*)&Bs[kk][tx * 8 + 4];
      #pragma unroll
      for (int i = 0; i < 8; ++i)
        #pragma unroll
        for (int j = 0; j < 8; ++j)
          acc[i][j] = fmaf(a8[i], b8[j], acc[i][j]);
    }
  }
  const int col = n0 + tx * 8;
  float bb[8];
  *(float4*)&bb[0] = *(const float4*)&bias[col];
  *(float4*)&bb[4] = *(const float4*)&bias[col + 4];
  #pragma unroll
  for (int i = 0; i < 8; ++i) {
    int row = m0 + ty * 8 + i;
    float4 o0, o1;
    o0.x = fmaxf(acc[i][0] + bb[0], 0.0f); o0.y = fmaxf(acc[i][1] + bb[1], 0.0f);
    o0.z = fmaxf(acc[i][2] + bb[2], 0.0f); o0.w = fmaxf(acc[i][3] + bb[3], 0.0f);
    o1.x = fmaxf(acc[i][4] + bb[4], 0.0f); o1.y = fmaxf(acc[i][5] + bb[5], 0.0f);
    o1.z = fmaxf(acc[i][6] + bb[6], 0.0f); o1.w = fmaxf(acc[i][7] + bb[7], 0.0f);
    *(float4*)&out[(size_t)row * VOC + col]     = o0;
    *(float4*)&out[(size_t)row * VOC + col + 4] = o1;
  }
}

extern "C" void kernel_launch(void* const* d_in, const int* in_sizes, int n_in,
                              void* d_out, int out_size, void* d_ws, size_t ws_size,
                              hipStream_t stream)
{
  if (ws_size < (size_t)WSEND * 4) return;  // visible-failure guard

  const int* enc_in  = (const int*)d_in[0];
  const int* enc_len = (const int*)d_in[1];
  const int* dec_in  = (const int*)d_in[2];
  const float* emb_src = (const float*)d_in[4];
  const float* emb_tgt = (const float*)d_in[5];
  const float* Wih_f = (const float*)d_in[6];
  const float* Whh_f = (const float*)d_in[7];
  const float* bih_f = (const float*)d_in[8];
  const float* bhh_f = (const float*)d_in[9];
  const float* Wih_b = (const float*)d_in[10];
  const float* Whh_b = (const float*)d_in[11];
  const float* bih_b = (const float*)d_in[12];
  const float* bhh_b = (const float*)d_in[13];
  const float* gWih  = (const float*)d_in[14];
  const float* gWhh  = (const float*)d_in[15];
  const float* gbih  = (const float*)d_in[16];
  const float* gbhh  = (const float*)d_in[17];
  const float* attn_W = (const float*)d_in[18];
  const float* attn_b = (const float*)d_in[19];
  const float* attn_v = (const float*)d_in[20];
  const float* clf_W = (const float*)d_in[21];
  const float* clf_b = (const float*)d_in[22];
  float* ws  = (float*)d_ws;
  float* out = (float*)d_out;

  hipMemsetAsync(d_ws, 0, 8192, stream);  // barrier lines (16 groups)
  scan_kernel<<<256, 512, 0, stream>>>(enc_in, enc_len, emb_src,
      Wih_f, Whh_f, bih_f, bhh_f, Wih_b, Whh_b, bih_b, bhh_b, ws);
  veo_kernel<<<dim3(NR / 128, (NB * TE) / 128), 256, 0, stream>>>(
      ws + OEO, gWih, (unsigned short*)(ws + OVEO));
  dec_kernel<<<256, 512, 0, stream>>>(dec_in, enc_len, emb_tgt,
      gWih, gWhh, gbih, gbhh, attn_W, attn_b, attn_v, ws);
  dim3 cg(VOC / 128, (NB * TD) / 128);
  clf_kernel<<<cg, 256, 0, stream>>>(ws + OHD, clf_W, clf_b, out);
}